// Round 6
// baseline (1113.514 us; speedup 1.0000x reference)
//
#include <hip/hip_runtime.h>
#include <hip/hip_bf16.h>

typedef __attribute__((ext_vector_type(8))) short short8;   // 8 x bf16 MFMA frag
typedef __attribute__((ext_vector_type(4))) float f32x4;
typedef __attribute__((ext_vector_type(4))) unsigned int uint4v;
typedef __attribute__((ext_vector_type(2))) unsigned int uint2v;

#define NB 16384
#define NH 1024
#define NE 64
#define ND 128
#define BR 32     // b-rows per k2 block
#define GRP 4     // P slices staged in LDS (ring, write-behind by 1 entity)

// ---------- bf16 helpers ----------
static __device__ __forceinline__ unsigned short f2b(float x) {
  unsigned int u = __builtin_bit_cast(unsigned int, x);
  unsigned int r = (u + 0x7fffu + ((u >> 16) & 1u)) >> 16;   // RNE, finite inputs
  return (unsigned short)r;
}
static __device__ __forceinline__ float b2f_lo(unsigned int u) {
  return __builtin_bit_cast(float, u << 16);
}
static __device__ __forceinline__ float b2f_hi(unsigned int u) {
  return __builtin_bit_cast(float, u & 0xffff0000u);
}

// raw barrier: drain LDS only (global stores keep flowing across barriers)
static __device__ __forceinline__ void bar_sync() {
  __builtin_amdgcn_sched_barrier(0);
  asm volatile("s_waitcnt lgkmcnt(0)" ::: "memory");
  __builtin_amdgcn_sched_barrier(0);
  __builtin_amdgcn_s_barrier();
  __builtin_amdgcn_sched_barrier(0);
}

// XOR-swizzled index into a [rows][128] bf16 tile; key row&15 is bijective
// over the 16 chunks of a 256B slice (16B chunks).
static __device__ __forceinline__ int swz(int row, int col) {
  return (row << 7) + ((((col >> 3) ^ (row & 15)) << 3) | (col & 7));
}
// same, for the [BR][GRP][128] staged-P ring (slice = row*GRP + eg)
static __device__ __forceinline__ int pswz(int row, int eg, int col) {
  return ((row * GRP + eg) << 7) + ((((col >> 3) ^ (row & 15)) << 3) | (col & 7));
}

// ---------- k0: prep (transposes + bias sum) ----------
__global__ __launch_bounds__(256, 1) void k0_prep(
    const float* __restrict__ Wh_w, const float* __restrict__ We_w,
    const float* __restrict__ We_b,
    unsigned short* __restrict__ WeT, unsigned short* __restrict__ WhT,
    float* __restrict__ bsum)
{
  __shared__ float tile[32][33];
  const int bid = blockIdx.x, t = threadIdx.x;
  const int i = t >> 5, j = t & 31;
  if (bid < 1024) {
    const int e = bid >> 4, tr = (bid >> 2) & 3, tc = bid & 3;
    const float* src = We_w + (size_t)e * 16384;
#pragma unroll
    for (int k = 0; k < 4; ++k)
      tile[i + 8 * k][j] = src[(size_t)(tr * 32 + i + 8 * k) * 128 + tc * 32 + j];
    __syncthreads();
    unsigned short* dst = WeT + (size_t)e * 16384;
#pragma unroll
    for (int k = 0; k < 4; ++k) {
      int row = i + 8 * k;
      dst[(size_t)(tc * 32 + row) * 128 + tr * 32 + j] = f2b(tile[j][row]);
    }
  } else if (bid < 1152) {
    const int tb = bid - 1024, tr = tb >> 2, tc = tb & 3;
#pragma unroll
    for (int k = 0; k < 4; ++k)
      tile[i + 8 * k][j] = Wh_w[(size_t)(tr * 32 + i + 8 * k) * 128 + tc * 32 + j];
    __syncthreads();
#pragma unroll
    for (int k = 0; k < 4; ++k) {
      int row = i + 8 * k;
      WhT[(size_t)(tc * 32 + row) * 1024 + tr * 32 + j] = f2b(tile[j][row]);
    }
  } else {
    if (t < 128) {
      float s = 0.f;
      for (int e = 0; e < 64; ++e) s += We_b[e * 128 + t];
      bsum[t] = s;
    }
  }
}

// ---------- k1: r = hidden @ Wh + Wh_b   -> r_bf16[B][128] ----------
// 512 blocks x 32 rows; wave w = (bg = w&1: rows 16bg..+15, dh = w>>1: d-half).
__global__ __launch_bounds__(256, 2) void k1_rgemm(
    const float* __restrict__ hidden, const unsigned short* __restrict__ WhT,
    const float* __restrict__ Wh_b, unsigned short* __restrict__ r_g)
{
  const int t = threadIdx.x;
  const int w = t >> 6, l = t & 63, c = l & 15, g = l >> 4;
  const int bg = w & 1, dh = w >> 1;
  const int b = blockIdx.x * 32 + 16 * bg + c;
  const float* hrow = hidden + (size_t)b * NH;
  f32x4 acc[4];
#pragma unroll
  for (int mf = 0; mf < 4; ++mf) acc[mf] = (f32x4){0.f, 0.f, 0.f, 0.f};
#pragma unroll 2
  for (int ks = 0; ks < 32; ++ks) {
    const int k0 = 8 * g + 32 * ks;
    f32x4 h0 = *(const f32x4*)(hrow + k0);
    f32x4 h1 = *(const f32x4*)(hrow + k0 + 4);
    short8 bf;
    bf[0] = (short)f2b(h0[0]); bf[1] = (short)f2b(h0[1]);
    bf[2] = (short)f2b(h0[2]); bf[3] = (short)f2b(h0[3]);
    bf[4] = (short)f2b(h1[0]); bf[5] = (short)f2b(h1[1]);
    bf[6] = (short)f2b(h1[2]); bf[7] = (short)f2b(h1[3]);
#pragma unroll
    for (int mf = 0; mf < 4; ++mf) {
      short8 af = *(const short8*)(WhT + (size_t)(64 * dh + 16 * mf + c) * NH + k0);
      acc[mf] = __builtin_amdgcn_mfma_f32_16x16x32_bf16(af, bf, acc[mf], 0, 0, 0);
    }
  }
#pragma unroll
  for (int mf = 0; mf < 4; ++mf) {
    const int d0 = 64 * dh + 16 * mf + 4 * g;
    f32x4 bias = *(const f32x4*)(Wh_b + d0);
    f32x4 v = acc[mf] + bias;
    unsigned int lo = (unsigned)f2b(v[0]) | ((unsigned)f2b(v[1]) << 16);
    unsigned int hi = (unsigned)f2b(v[2]) | ((unsigned)f2b(v[3]) << 16);
    uint2v pk = {lo, hi};
    *(uint2v*)(r_g + (size_t)b * ND + d0) = pk;
  }
}

// ---------- k2: main fused kernel (512 blocks x 32 rows, 2 blocks/CU) ----------
struct SmemK2 {
  union {
    unsigned short Pst[BR * GRP * 128];   // 32KB P ring (4 entity slices)
    float obuf[BR * 128];                 // 16KB, epilogue reuse
  };
  unsigned short r_lds[BR * 128];         // 8KB, swizzled
  float sms[4][BR];                       // cross-wave sum partials
};

// prefetch next entity's We fragments + bias (both L2-resident)
static __device__ __forceinline__ void load_we_frags(
    short8 (&f)[2][4], f32x4 (&bias)[2],
    const unsigned short* __restrict__ WeT, const float* __restrict__ We_b,
    int e, int w, int c, int g)
{
  const unsigned short* base = WeT + (size_t)e * (ND * ND);
#pragma unroll
  for (int mf = 0; mf < 2; ++mf) {
    const unsigned short* rowp = base + (size_t)(16 * (2 * w + mf) + c) * ND + 8 * g;
#pragma unroll
    for (int ks = 0; ks < 4; ++ks)
      f[mf][ks] = *(const short8*)(rowp + 32 * ks);
    bias[mf] = *(const f32x4*)(We_b + e * ND + 32 * w + 16 * mf + 4 * g);
  }
}

// write-behind: stream one staged P slice (16KB/block) to global with nt
// stores. Per instruction: 8 rows x 8 lanes x 16B (contiguous 128B per row).
static __device__ __forceinline__ void store_p_slice(
    const SmemK2& sm, float* __restrict__ outP,
    int brow0, int e_prev, int slice, int t)
{
  const int row = t >> 3;
  const int c0 = (t & 7) * 16;
  uint4v u0 = *(const uint4v*)(&sm.Pst[pswz(row, slice, c0)]);
  uint4v u1 = *(const uint4v*)(&sm.Pst[pswz(row, slice, c0 + 8)]);
  float* dst = outP + ((size_t)(brow0 + row) * NE + e_prev) * ND + c0;
  f32x4 v;
  v[0]=b2f_lo(u0[0]); v[1]=b2f_hi(u0[0]); v[2]=b2f_lo(u0[1]); v[3]=b2f_hi(u0[1]);
  __builtin_nontemporal_store(v, (f32x4*)(dst));
  v[0]=b2f_lo(u0[2]); v[1]=b2f_hi(u0[2]); v[2]=b2f_lo(u0[3]); v[3]=b2f_hi(u0[3]);
  __builtin_nontemporal_store(v, (f32x4*)(dst + 4));
  v[0]=b2f_lo(u1[0]); v[1]=b2f_hi(u1[0]); v[2]=b2f_lo(u1[1]); v[3]=b2f_hi(u1[1]);
  __builtin_nontemporal_store(v, (f32x4*)(dst + 8));
  v[0]=b2f_lo(u1[2]); v[1]=b2f_hi(u1[2]); v[2]=b2f_lo(u1[3]); v[3]=b2f_hi(u1[3]);
  __builtin_nontemporal_store(v, (f32x4*)(dst + 12));
}

static __device__ __forceinline__ void entity_body(
    int i, int en, int e_prev, bool do_store,
    int brow0, int w, int c, int g, int t,
    short8 (&cur)[2][4], short8 (&nxt)[2][4],
    f32x4 (&bcur)[2], f32x4 (&bnxt)[2], f32x4 (&acc2)[2][2],
    const unsigned short* __restrict__ WeT, const float* __restrict__ We_b,
    float* __restrict__ outP, SmemK2& sm)
{
  const int eg = i & 3, pg = (i + 3) & 3;
  // ---- GEMM1: L^T[d][b], wave w owns d in [32w, 32w+32)
  f32x4 acc1[2][2];
#pragma unroll
  for (int mf = 0; mf < 2; ++mf)
#pragma unroll
    for (int nf = 0; nf < 2; ++nf) acc1[mf][nf] = (f32x4){0.f, 0.f, 0.f, 0.f};
#pragma unroll
  for (int ks = 0; ks < 4; ++ks) {
    short8 b1[2];
#pragma unroll
    for (int nf = 0; nf < 2; ++nf)
      b1[nf] = *(const short8*)(&sm.r_lds[swz(16 * nf + c, 8 * g + 32 * ks)]);
#pragma unroll
    for (int mf = 0; mf < 2; ++mf)
#pragma unroll
      for (int nf = 0; nf < 2; ++nf)
        acc1[mf][nf] = __builtin_amdgcn_mfma_f32_16x16x32_bf16(
            cur[mf][ks], b1[nf], acc1[mf][nf], 0, 0, 0);
  }
  // ALL loads for the next entity issue BEFORE this entity's stores: every
  // later vmcnt wait then targets loads older than any outstanding store,
  // so (in-order retirement) no wait ever requires a store to retire.
  load_we_frags(nxt, bnxt, WeT, We_b, en, w, c, g);
  __builtin_amdgcn_sched_barrier(0);
  // ---- write-behind: stream previous entity's P slice (smooth store flow)
  if (do_store) store_p_slice(sm, outP, brow0, e_prev, pg, t);

  // ---- bias + exp + sum (no max-pass: |logits| <~ 1 for this problem)
#pragma unroll
  for (int mf = 0; mf < 2; ++mf)
#pragma unroll
    for (int nf = 0; nf < 2; ++nf) acc1[mf][nf] += bcur[mf];
  float s[2] = {0.f, 0.f};
#pragma unroll
  for (int nf = 0; nf < 2; ++nf) {
#pragma unroll
    for (int mf = 0; mf < 2; ++mf)
#pragma unroll
      for (int r = 0; r < 4; ++r) {
        float p = __expf(acc1[mf][nf][r]);
        acc1[mf][nf][r] = p;
        s[nf] += p;
      }
    s[nf] += __shfl_xor(s[nf], 16);
    s[nf] += __shfl_xor(s[nf], 32);
  }
  if (g == 0) {
#pragma unroll
    for (int nf = 0; nf < 2; ++nf) sm.sms[w][16 * nf + c] = s[nf];
  }
  bar_sync();                                   // barrier 1
  float inv[2];
#pragma unroll
  for (int nf = 0; nf < 2; ++nf) {
    int b = 16 * nf + c;
    inv[nf] = 1.f / (sm.sms[0][b] + sm.sms[1][b] + sm.sms[2][b] + sm.sms[3][b]);
  }
  // ---- normalize, pack bf16, write staged P slice eg (swizzled)
#pragma unroll
  for (int mf = 0; mf < 2; ++mf)
#pragma unroll
    for (int nf = 0; nf < 2; ++nf) {
      f32x4 p = acc1[mf][nf] * inv[nf];
      unsigned int lo = (unsigned)f2b(p[0]) | ((unsigned)f2b(p[1]) << 16);
      unsigned int hi = (unsigned)f2b(p[2]) | ((unsigned)f2b(p[3]) << 16);
      uint2v pk = {lo, hi};
      *(uint2v*)(&sm.Pst[pswz(16 * nf + c, eg, 32 * w + 16 * mf + 4 * g)]) = pk;
    }
  bar_sync();                                   // barrier 2

  // ---- GEMM2: acc2[b][d'] += P x We (reuses cur as B operand)
#pragma unroll
  for (int ks = 0; ks < 4; ++ks) {
    short8 a2[2];
#pragma unroll
    for (int mf2 = 0; mf2 < 2; ++mf2)
      a2[mf2] = *(const short8*)(&sm.Pst[pswz(16 * mf2 + c, eg, 8 * g + 32 * ks)]);
#pragma unroll
    for (int mf2 = 0; mf2 < 2; ++mf2)
#pragma unroll
      for (int n = 0; n < 2; ++n)
        acc2[mf2][n] = __builtin_amdgcn_mfma_f32_16x16x32_bf16(
            a2[mf2], cur[n][ks], acc2[mf2][n], 0, 0, 0);
  }
}

__global__ __launch_bounds__(256, 2) void k2_main(
    const unsigned short* __restrict__ r_g, const unsigned short* __restrict__ WeT,
    const float* __restrict__ We_b, const float* __restrict__ bsum,
    float* __restrict__ outP, float* __restrict__ outR)
{
  __shared__ SmemK2 sm;
  const int t = threadIdx.x;
  const int w = t >> 6, l = t & 63, c = l & 15, g = l >> 4;
  // XCD-bijective remap: XCD x owns logical blocks [x*64, x*64+64)
  const int lb = (blockIdx.x & 7) * 64 + (blockIdx.x >> 3);
  const int brow0 = lb * BR;
  // phase-stagger: co-resident blocks get different e0
  const int e0 = (((lb >> 6) + lb) & 7) << 3;

  // stage r tile (32 x 128 bf16, swizzled) — fully contiguous global reads
  for (int i = t; i < BR * 16; i += 256) {
    int row = i >> 4, ch = i & 15;
    uint4v v = *(const uint4v*)(r_g + (size_t)(brow0 + row) * ND + ch * 8);
    *(uint4v*)(&sm.r_lds[swz(row, ch * 8)]) = v;
  }
  const float bs0 = bsum[32 * w + c];
  const float bs1 = bsum[32 * w + 16 + c];

  f32x4 acc2[2][2];
#pragma unroll
  for (int i = 0; i < 2; ++i)
#pragma unroll
    for (int j = 0; j < 2; ++j) acc2[i][j] = (f32x4){0.f, 0.f, 0.f, 0.f};

  short8 wa[2][4], wb[2][4];
  f32x4 ba[2], bb[2];
  load_we_frags(wa, ba, WeT, We_b, e0, w, c, g);
  bar_sync();

#pragma unroll 1
  for (int i = 0; i < NE; i += 2) {             // ping-pong, statically indexed
    const int eB = (e0 + i + 1) & 63, eC = (e0 + i + 2) & 63;
    const int pA = (e0 + i + 63) & 63, pB = (e0 + i) & 63;
    entity_body(i,     eB, pA, i > 0, brow0, w, c, g, t,
                wa, wb, ba, bb, acc2, WeT, We_b, outP, sm);
    entity_body(i + 1, eC, pB, true,  brow0, w, c, g, t,
                wb, wa, bb, ba, acc2, WeT, We_b, outP, sm);
  }
  // drain: final entity's slice (ring slot 3)
  store_p_slice(sm, outP, brow0, (e0 + 63) & 63, 3, t);

  // ---- epilogue: result[b][d'] via LDS transpose, coalesced nt store
  bar_sync();                 // lgkmcnt(0) also protects Pst reads vs obuf
#pragma unroll
  for (int mf2 = 0; mf2 < 2; ++mf2)
#pragma unroll
    for (int n = 0; n < 2; ++n) {
      float bs = n ? bs1 : bs0;
#pragma unroll
      for (int r = 0; r < 4; ++r)
        sm.obuf[(16 * mf2 + 4 * g + r) * ND + 32 * w + 16 * n + c] =
            acc2[mf2][n][r] + bs;
    }
  bar_sync();
  {
    const int orow = t >> 5, ocol = (t & 31) * 4;
#pragma unroll
    for (int it = 0; it < 4; ++it) {
      const int row = orow + 8 * it;
      f32x4 v = *(const f32x4*)(&sm.obuf[row * ND + ocol]);
      __builtin_nontemporal_store(
          v, (f32x4*)(outR + (size_t)(brow0 + row) * ND + ocol));
    }
  }
}

extern "C" void kernel_launch(void* const* d_in, const int* in_sizes, int n_in,
                              void* d_out, int out_size, void* d_ws, size_t ws_size,
                              hipStream_t stream)
{
  (void)in_sizes; (void)n_in; (void)out_size; (void)ws_size;
  const float* hidden = (const float*)d_in[0];
  const float* Wh_w   = (const float*)d_in[1];
  const float* Wh_b   = (const float*)d_in[2];
  const float* We_w   = (const float*)d_in[3];
  const float* We_b   = (const float*)d_in[4];
  float* outP = (float*)d_out;
  float* outR = outP + (size_t)NB * NE * ND;

  char* ws = (char*)d_ws;
  unsigned short* WeT = (unsigned short*)(ws);
  unsigned short* WhT = (unsigned short*)(ws + 2097152);
  unsigned short* r_g = (unsigned short*)(ws + 2097152 + 262144);
  float* bsum         = (float*)(ws + 2097152 + 262144 + 4194304);

  k0_prep<<<1153, 256, 0, stream>>>(Wh_w, We_w, We_b, WeT, WhT, bsum);
  k1_rgemm<<<512, 256, 0, stream>>>(hidden, WhT, Wh_b, r_g);
  k2_main<<<512, 256, 0, stream>>>(r_g, WeT, We_b, bsum, outP, outR);
}

// Round 7
// 223.036 us; speedup vs baseline: 4.9925x; 4.9925x over previous
//
#include <hip/hip_runtime.h>
#include <hip/hip_bf16.h>

typedef __attribute__((ext_vector_type(8))) short short8;   // 8 x bf16 MFMA frag
typedef __attribute__((ext_vector_type(4))) float f32x4;
typedef __attribute__((ext_vector_type(4))) unsigned int uint4v;
typedef __attribute__((ext_vector_type(2))) unsigned int uint2v;

#define NB 16384
#define NH 1024
#define NE 64
#define ND 128
#define BR 32     // b-rows per k2 block
#define GRP 4     // P slices staged in LDS (ring, write-behind by 1 entity)

// ---------- bf16 helpers ----------
static __device__ __forceinline__ unsigned short f2b(float x) {
  unsigned int u = __builtin_bit_cast(unsigned int, x);
  unsigned int r = (u + 0x7fffu + ((u >> 16) & 1u)) >> 16;   // RNE, finite inputs
  return (unsigned short)r;
}
static __device__ __forceinline__ float b2f_lo(unsigned int u) {
  return __builtin_bit_cast(float, u << 16);
}
static __device__ __forceinline__ float b2f_hi(unsigned int u) {
  return __builtin_bit_cast(float, u & 0xffff0000u);
}

// raw barrier: drain LDS only (global stores keep flowing across barriers)
static __device__ __forceinline__ void bar_sync() {
  __builtin_amdgcn_sched_barrier(0);
  asm volatile("s_waitcnt lgkmcnt(0)" ::: "memory");
  __builtin_amdgcn_sched_barrier(0);
  __builtin_amdgcn_s_barrier();
  __builtin_amdgcn_sched_barrier(0);
}

// XOR-swizzled index into a [rows][128] bf16 tile; key row&15 is bijective
// over the 16 chunks of a 256B slice (16B chunks).
static __device__ __forceinline__ int swz(int row, int col) {
  return (row << 7) + ((((col >> 3) ^ (row & 15)) << 3) | (col & 7));
}
// same, for the [BR][GRP][128] staged-P ring (slice = row*GRP + eg)
static __device__ __forceinline__ int pswz(int row, int eg, int col) {
  return ((row * GRP + eg) << 7) + ((((col >> 3) ^ (row & 15)) << 3) | (col & 7));
}

// ---------- k0: prep (transposes + bias sum) ----------
__global__ __launch_bounds__(256, 1) void k0_prep(
    const float* __restrict__ Wh_w, const float* __restrict__ We_w,
    const float* __restrict__ We_b,
    unsigned short* __restrict__ WeT, unsigned short* __restrict__ WhT,
    float* __restrict__ bsum)
{
  __shared__ float tile[32][33];
  const int bid = blockIdx.x, t = threadIdx.x;
  const int i = t >> 5, j = t & 31;
  if (bid < 1024) {
    const int e = bid >> 4, tr = (bid >> 2) & 3, tc = bid & 3;
    const float* src = We_w + (size_t)e * 16384;
#pragma unroll
    for (int k = 0; k < 4; ++k)
      tile[i + 8 * k][j] = src[(size_t)(tr * 32 + i + 8 * k) * 128 + tc * 32 + j];
    __syncthreads();
    unsigned short* dst = WeT + (size_t)e * 16384;
#pragma unroll
    for (int k = 0; k < 4; ++k) {
      int row = i + 8 * k;
      dst[(size_t)(tc * 32 + row) * 128 + tr * 32 + j] = f2b(tile[j][row]);
    }
  } else if (bid < 1152) {
    const int tb = bid - 1024, tr = tb >> 2, tc = tb & 3;
#pragma unroll
    for (int k = 0; k < 4; ++k)
      tile[i + 8 * k][j] = Wh_w[(size_t)(tr * 32 + i + 8 * k) * 128 + tc * 32 + j];
    __syncthreads();
#pragma unroll
    for (int k = 0; k < 4; ++k) {
      int row = i + 8 * k;
      WhT[(size_t)(tc * 32 + row) * 1024 + tr * 32 + j] = f2b(tile[j][row]);
    }
  } else {
    if (t < 128) {
      float s = 0.f;
      for (int e = 0; e < 64; ++e) s += We_b[e * 128 + t];
      bsum[t] = s;
    }
  }
}

// ---------- k1: r = hidden @ Wh + Wh_b   -> r_bf16[B][128] ----------
// 512 blocks x 32 rows; wave w = (bg = w&1: rows 16bg..+15, dh = w>>1: d-half).
__global__ __launch_bounds__(256, 2) void k1_rgemm(
    const float* __restrict__ hidden, const unsigned short* __restrict__ WhT,
    const float* __restrict__ Wh_b, unsigned short* __restrict__ r_g)
{
  const int t = threadIdx.x;
  const int w = t >> 6, l = t & 63, c = l & 15, g = l >> 4;
  const int bg = w & 1, dh = w >> 1;
  const int b = blockIdx.x * 32 + 16 * bg + c;
  const float* hrow = hidden + (size_t)b * NH;
  f32x4 acc[4];
#pragma unroll
  for (int mf = 0; mf < 4; ++mf) acc[mf] = (f32x4){0.f, 0.f, 0.f, 0.f};
#pragma unroll 2
  for (int ks = 0; ks < 32; ++ks) {
    const int k0 = 8 * g + 32 * ks;
    f32x4 h0 = *(const f32x4*)(hrow + k0);
    f32x4 h1 = *(const f32x4*)(hrow + k0 + 4);
    short8 bf;
    bf[0] = (short)f2b(h0[0]); bf[1] = (short)f2b(h0[1]);
    bf[2] = (short)f2b(h0[2]); bf[3] = (short)f2b(h0[3]);
    bf[4] = (short)f2b(h1[0]); bf[5] = (short)f2b(h1[1]);
    bf[6] = (short)f2b(h1[2]); bf[7] = (short)f2b(h1[3]);
#pragma unroll
    for (int mf = 0; mf < 4; ++mf) {
      short8 af = *(const short8*)(WhT + (size_t)(64 * dh + 16 * mf + c) * NH + k0);
      acc[mf] = __builtin_amdgcn_mfma_f32_16x16x32_bf16(af, bf, acc[mf], 0, 0, 0);
    }
  }
#pragma unroll
  for (int mf = 0; mf < 4; ++mf) {
    const int d0 = 64 * dh + 16 * mf + 4 * g;
    f32x4 bias = *(const f32x4*)(Wh_b + d0);
    f32x4 v = acc[mf] + bias;
    unsigned int lo = (unsigned)f2b(v[0]) | ((unsigned)f2b(v[1]) << 16);
    unsigned int hi = (unsigned)f2b(v[2]) | ((unsigned)f2b(v[3]) << 16);
    uint2v pk = {lo, hi};
    *(uint2v*)(r_g + (size_t)b * ND + d0) = pk;
  }
}

// ---------- k2: main fused kernel (512 blocks x 32 rows, 2 blocks/CU) ----------
struct SmemK2 {
  union {
    unsigned short Pst[BR * GRP * 128];   // 32KB P ring (4 entity slices)
    float obuf[BR * 128];                 // 16KB, epilogue reuse
  };
  unsigned short r_lds[BR * 128];         // 8KB, swizzled
  float sms[4][BR];                       // cross-wave sum partials
};

// prefetch next entity's We fragments + bias (both L2-resident)
static __device__ __forceinline__ void load_we_frags(
    short8 (&f)[2][4], f32x4 (&bias)[2],
    const unsigned short* __restrict__ WeT, const float* __restrict__ We_b,
    int e, int w, int c, int g)
{
  const unsigned short* base = WeT + (size_t)e * (ND * ND);
#pragma unroll
  for (int mf = 0; mf < 2; ++mf) {
    const unsigned short* rowp = base + (size_t)(16 * (2 * w + mf) + c) * ND + 8 * g;
#pragma unroll
    for (int ks = 0; ks < 4; ++ks)
      f[mf][ks] = *(const short8*)(rowp + 32 * ks);
    bias[mf] = *(const f32x4*)(We_b + e * ND + 32 * w + 16 * mf + 4 * g);
  }
}

// write-behind: stream one staged P slice (16KB f32/block) to global with nt
// stores. Per instruction: 64 lanes x contiguous 16B = two aligned 512B runs
// (full-line coverage; nt needs >=512B contiguity — round-6 lesson).
static __device__ __forceinline__ void store_p_slice(
    const SmemK2& sm, float* __restrict__ outP,
    int brow0, int e_prev, int slice, int t)
{
#pragma unroll
  for (int it = 0; it < 4; ++it) {
    const int flat = it * 1024 + t * 4;      // float idx in [0, BR*ND)
    const int row = flat >> 7;
    const int col = flat & 127;
    uint2v u = *(const uint2v*)(&sm.Pst[pswz(row, slice, col)]);
    f32x4 v;
    v[0] = b2f_lo(u[0]); v[1] = b2f_hi(u[0]);
    v[2] = b2f_lo(u[1]); v[3] = b2f_hi(u[1]);
    float* dst = outP + ((size_t)(brow0 + row) * NE + e_prev) * ND + col;
    __builtin_nontemporal_store(v, (f32x4*)dst);
  }
}

static __device__ __forceinline__ void entity_body(
    int i, int en, int e_prev, bool do_store,
    int brow0, int w, int c, int g, int t,
    short8 (&cur)[2][4], short8 (&nxt)[2][4],
    f32x4 (&bcur)[2], f32x4 (&bnxt)[2], f32x4 (&acc2)[2][2],
    const unsigned short* __restrict__ WeT, const float* __restrict__ We_b,
    float* __restrict__ outP, SmemK2& sm)
{
  const int eg = i & 3, pg = (i + 3) & 3;
  // ---- GEMM1: L^T[d][b], wave w owns d in [32w, 32w+32)
  f32x4 acc1[2][2];
#pragma unroll
  for (int mf = 0; mf < 2; ++mf)
#pragma unroll
    for (int nf = 0; nf < 2; ++nf) acc1[mf][nf] = (f32x4){0.f, 0.f, 0.f, 0.f};
#pragma unroll
  for (int ks = 0; ks < 4; ++ks) {
    short8 b1[2];
#pragma unroll
    for (int nf = 0; nf < 2; ++nf)
      b1[nf] = *(const short8*)(&sm.r_lds[swz(16 * nf + c, 8 * g + 32 * ks)]);
#pragma unroll
    for (int mf = 0; mf < 2; ++mf)
#pragma unroll
      for (int nf = 0; nf < 2; ++nf)
        acc1[mf][nf] = __builtin_amdgcn_mfma_f32_16x16x32_bf16(
            cur[mf][ks], b1[nf], acc1[mf][nf], 0, 0, 0);
  }
  // ALL loads for the next entity issue BEFORE this entity's stores: every
  // later vmcnt wait then targets loads older than any outstanding store,
  // so (in-order retirement) no wait ever requires a store to retire.
  load_we_frags(nxt, bnxt, WeT, We_b, en, w, c, g);
  __builtin_amdgcn_sched_barrier(0);
  // ---- write-behind: stream previous entity's P slice (smooth store flow)
  if (do_store) store_p_slice(sm, outP, brow0, e_prev, pg, t);

  // ---- bias + exp + sum (no max-pass: |logits| <~ 1 for this problem)
#pragma unroll
  for (int mf = 0; mf < 2; ++mf)
#pragma unroll
    for (int nf = 0; nf < 2; ++nf) acc1[mf][nf] += bcur[mf];
  float s[2] = {0.f, 0.f};
#pragma unroll
  for (int nf = 0; nf < 2; ++nf) {
#pragma unroll
    for (int mf = 0; mf < 2; ++mf)
#pragma unroll
      for (int r = 0; r < 4; ++r) {
        float p = __expf(acc1[mf][nf][r]);
        acc1[mf][nf][r] = p;
        s[nf] += p;
      }
    s[nf] += __shfl_xor(s[nf], 16);
    s[nf] += __shfl_xor(s[nf], 32);
  }
  if (g == 0) {
#pragma unroll
    for (int nf = 0; nf < 2; ++nf) sm.sms[w][16 * nf + c] = s[nf];
  }
  bar_sync();                                   // barrier 1
  float inv[2];
#pragma unroll
  for (int nf = 0; nf < 2; ++nf) {
    int b = 16 * nf + c;
    inv[nf] = 1.f / (sm.sms[0][b] + sm.sms[1][b] + sm.sms[2][b] + sm.sms[3][b]);
  }
  // ---- normalize, pack bf16, write staged P slice eg (swizzled)
#pragma unroll
  for (int mf = 0; mf < 2; ++mf)
#pragma unroll
    for (int nf = 0; nf < 2; ++nf) {
      f32x4 p = acc1[mf][nf] * inv[nf];
      unsigned int lo = (unsigned)f2b(p[0]) | ((unsigned)f2b(p[1]) << 16);
      unsigned int hi = (unsigned)f2b(p[2]) | ((unsigned)f2b(p[3]) << 16);
      uint2v pk = {lo, hi};
      *(uint2v*)(&sm.Pst[pswz(16 * nf + c, eg, 32 * w + 16 * mf + 4 * g)]) = pk;
    }
  bar_sync();                                   // barrier 2

  // ---- GEMM2: acc2[b][d'] += P x We (reuses cur as B operand)
#pragma unroll
  for (int ks = 0; ks < 4; ++ks) {
    short8 a2[2];
#pragma unroll
    for (int mf2 = 0; mf2 < 2; ++mf2)
      a2[mf2] = *(const short8*)(&sm.Pst[pswz(16 * mf2 + c, eg, 8 * g + 32 * ks)]);
#pragma unroll
    for (int mf2 = 0; mf2 < 2; ++mf2)
#pragma unroll
      for (int n = 0; n < 2; ++n)
        acc2[mf2][n] = __builtin_amdgcn_mfma_f32_16x16x32_bf16(
            a2[mf2], cur[n][ks], acc2[mf2][n], 0, 0, 0);
  }
}

__global__ __launch_bounds__(256, 2) void k2_main(
    const unsigned short* __restrict__ r_g, const unsigned short* __restrict__ WeT,
    const float* __restrict__ We_b, const float* __restrict__ bsum,
    float* __restrict__ outP, float* __restrict__ outR)
{
  __shared__ SmemK2 sm;
  const int t = threadIdx.x;
  const int w = t >> 6, l = t & 63, c = l & 15, g = l >> 4;
  // XCD-bijective remap: XCD x owns logical blocks [x*64, x*64+64)
  const int lb = (blockIdx.x & 7) * 64 + (blockIdx.x >> 3);
  const int brow0 = lb * BR;
  // phase-stagger: co-resident blocks get different e0
  const int e0 = (((lb >> 6) + lb) & 7) << 3;

  // stage r tile (32 x 128 bf16, swizzled) — fully contiguous global reads
  for (int i = t; i < BR * 16; i += 256) {
    int row = i >> 4, ch = i & 15;
    uint4v v = *(const uint4v*)(r_g + (size_t)(brow0 + row) * ND + ch * 8);
    *(uint4v*)(&sm.r_lds[swz(row, ch * 8)]) = v;
  }
  const float bs0 = bsum[32 * w + c];
  const float bs1 = bsum[32 * w + 16 + c];

  f32x4 acc2[2][2];
#pragma unroll
  for (int i = 0; i < 2; ++i)
#pragma unroll
    for (int j = 0; j < 2; ++j) acc2[i][j] = (f32x4){0.f, 0.f, 0.f, 0.f};

  short8 wa[2][4], wb[2][4];
  f32x4 ba[2], bb[2];
  load_we_frags(wa, ba, WeT, We_b, e0, w, c, g);
  bar_sync();

#pragma unroll 1
  for (int i = 0; i < NE; i += 2) {             // ping-pong, statically indexed
    const int eB = (e0 + i + 1) & 63, eC = (e0 + i + 2) & 63;
    const int pA = (e0 + i + 63) & 63, pB = (e0 + i) & 63;
    entity_body(i,     eB, pA, i > 0, brow0, w, c, g, t,
                wa, wb, ba, bb, acc2, WeT, We_b, outP, sm);
    entity_body(i + 1, eC, pB, true,  brow0, w, c, g, t,
                wb, wa, bb, ba, acc2, WeT, We_b, outP, sm);
  }
  // drain: final entity's slice (ring slot 3)
  store_p_slice(sm, outP, brow0, (e0 + 63) & 63, 3, t);

  // ---- epilogue: result[b][d'] via LDS transpose, coalesced nt store
  bar_sync();                 // lgkmcnt(0) also protects Pst reads vs obuf
#pragma unroll
  for (int mf2 = 0; mf2 < 2; ++mf2)
#pragma unroll
    for (int n = 0; n < 2; ++n) {
      float bs = n ? bs1 : bs0;
#pragma unroll
      for (int r = 0; r < 4; ++r)
        sm.obuf[(16 * mf2 + 4 * g + r) * ND + 32 * w + 16 * n + c] =
            acc2[mf2][n][r] + bs;
    }
  bar_sync();
  {
    const int orow = t >> 5, ocol = (t & 31) * 4;
#pragma unroll
    for (int it = 0; it < 4; ++it) {
      const int row = orow + 8 * it;
      f32x4 v = *(const f32x4*)(&sm.obuf[row * ND + ocol]);
      __builtin_nontemporal_store(
          v, (f32x4*)(outR + (size_t)(brow0 + row) * ND + ocol));
    }
  }
}

extern "C" void kernel_launch(void* const* d_in, const int* in_sizes, int n_in,
                              void* d_out, int out_size, void* d_ws, size_t ws_size,
                              hipStream_t stream)
{
  (void)in_sizes; (void)n_in; (void)out_size; (void)ws_size;
  const float* hidden = (const float*)d_in[0];
  const float* Wh_w   = (const float*)d_in[1];
  const float* Wh_b   = (const float*)d_in[2];
  const float* We_w   = (const float*)d_in[3];
  const float* We_b   = (const float*)d_in[4];
  float* outP = (float*)d_out;
  float* outR = outP + (size_t)NB * NE * ND;

  char* ws = (char*)d_ws;
  unsigned short* WeT = (unsigned short*)(ws);
  unsigned short* WhT = (unsigned short*)(ws + 2097152);
  unsigned short* r_g = (unsigned short*)(ws + 2097152 + 262144);
  float* bsum         = (float*)(ws + 2097152 + 262144 + 4194304);

  k0_prep<<<1153, 256, 0, stream>>>(Wh_w, We_w, We_b, WeT, WhT, bsum);
  k1_rgemm<<<512, 256, 0, stream>>>(hidden, WhT, Wh_b, r_g);
  k2_main<<<512, 256, 0, stream>>>(r_g, WeT, We_b, bsum, outP, outR);
}